// Round 11
// baseline (995.755 us; speedup 1.0000x reference)
//
#include <hip/hip_runtime.h>

// PlasticLSTM: T=256, B=32, I=128, H=256, 4H=1024, CLIP=2
// d_out: hs[T,B,H] ++ h[B,H] ++ c[B,H] ++ hebb[B,H,H]  (fp32, concat flat)
//
// Round-11: 8-way split-K — 256 blocks (full chip), role r = bid>>5 owns rows
// r*32..r*32+31 of the Wh dot, hebb, alpha. Weights/alpha/hebb all register-
// resident (~70 VGPR << 128 wall). Publish-early schedule: matvec first,
// f/i/o-quarter parts published before phase 1a (visibility hidden behind
// hebb+plast compute); j-quarter published after the plast fold; single
// tagged {t+1|f32} u64 per element is its own signal (round-10 protocol,
// clobber-safety proof unchanged).

#define TT 256
#define BB 32
#define II 128
#define HH 256
#define G4 1024

typedef _Float16 h2_t __attribute__((ext_vector_type(2)));
typedef unsigned long long u64;

__device__ __forceinline__ float sigm(float x) {
    return 1.0f / (1.0f + __expf(-x));
}
__device__ __forceinline__ float tanhfast(float x) {
    return 1.0f - 2.0f / (__expf(2.0f * x) + 1.0f);
}
__device__ __forceinline__ unsigned pkh(float lo, float hi) {
    h2_t v;
    v.x = (_Float16)lo;
    v.y = (_Float16)hi;
    return __builtin_bit_cast(unsigned, v);
}

#if __has_builtin(__builtin_amdgcn_fdot2)
__device__ __forceinline__ float dot2(unsigned a, unsigned b, float c) {
    return __builtin_amdgcn_fdot2(__builtin_bit_cast(h2_t, a),
                                  __builtin_bit_cast(h2_t, b), c, false);
}
#else
__device__ __forceinline__ float dot2(unsigned a, unsigned b, float c) {
    h2_t av = __builtin_bit_cast(h2_t, a), bv = __builtin_bit_cast(h2_t, b);
    return c + (float)av.x * (float)bv.x + (float)av.y * (float)bv.y;
}
#endif

__device__ __forceinline__ h2_t pkfma(h2_t a, h2_t b, h2_t c) {
#if __has_builtin(__builtin_elementwise_fma)
    return __builtin_elementwise_fma(a, b, c);
#else
    return a * b + c;
#endif
}
__device__ __forceinline__ h2_t clip2h(h2_t x) {
    const h2_t lo = {(_Float16)-2.0f, (_Float16)-2.0f};
    const h2_t hi = {(_Float16)2.0f, (_Float16)2.0f};
#if __has_builtin(__builtin_elementwise_max) && __has_builtin(__builtin_elementwise_min)
    return __builtin_elementwise_min(__builtin_elementwise_max(x, lo), hi);
#else
    h2_t r = x;
    r.x = r.x < lo.x ? lo.x : (r.x > hi.x ? hi.x : r.x);
    r.y = r.y < lo.y ? lo.y : (r.y > hi.y ? hi.y : r.y);
    return r;
#endif
}

// ---------------------------------------------------------------------------
// Wd3: idx = ro*4096 + g*4 + ri ; entry = 8 f16 of Wh[g][8*(4ro+ri) .. +7]
// ---------------------------------------------------------------------------
__global__ __launch_bounds__(256) void prep_wd3(const float* __restrict__ Wh,
                                                uint4* __restrict__ Wd3) {
    int idx = blockIdx.x * 256 + threadIdx.x;   // 32768
    int ro = idx >> 12, rem = idx & 4095;
    int g = rem >> 2, ri = rem & 3;
    int r8 = 4 * ro + ri;
    const float4* s = (const float4*)(Wh + (size_t)g * HH + (r8 << 3));
    float4 a = s[0], b2 = s[1];
    uint4 o;
    o.x = pkh(a.x, a.y);
    o.y = pkh(a.z, a.w);
    o.z = pkh(b2.x, b2.y);
    o.w = pkh(b2.z, b2.w);
    Wd3[idx] = o;
}

// ---------------------------------------------------------------------------
// alQ: idx = p4*256 + k -> uint4; comp j = f16 pair {alpha[2*(4p4+j)][k], +1}
// ---------------------------------------------------------------------------
__global__ __launch_bounds__(256) void prep_alq(const float* __restrict__ alpha,
                                                uint4* __restrict__ alQ) {
    int idx = blockIdx.x * 256 + threadIdx.x;   // 8192
    int p4 = idx >> 8, k = idx & 255;
    unsigned r[4];
#pragma unroll
    for (int j = 0; j < 4; ++j) {
        int p = 4 * p4 + j;
        float a0 = alpha[(size_t)(2 * p) * HH + k];
        float a1 = alpha[(size_t)(2 * p + 1) * HH + k];
        r[j] = pkh(a0, a1);
    }
    uint4 o; o.x = r[0]; o.y = r[1]; o.z = r[2]; o.w = r[3];
    alQ[idx] = o;
}

// ---------------------------------------------------------------------------
// xf[t,b,g] = sum_i x[t,b,i]*Wx[g,i] + bx[g] + bh[g]
// ---------------------------------------------------------------------------
__global__ __launch_bounds__(256) void xf_gemm(const float* __restrict__ x,
                                               const float* __restrict__ Wx,
                                               const float* __restrict__ bx,
                                               const float* __restrict__ bh,
                                               float* __restrict__ xf) {
    __shared__ float As[64][37];
    __shared__ float Bs[64][37];
    const int tid = threadIdx.x;
    const int tx = tid & 15, ty = tid >> 4;
    const int m0 = blockIdx.y << 6;
    const int n0 = blockIdx.x << 6;
    float c[4][4] = {};

    for (int k0 = 0; k0 < II; k0 += 32) {
#pragma unroll
        for (int hh = 0; hh < 2; ++hh) {
            int row = (tid >> 3) + (hh << 5);
            int col = (tid & 7) << 2;
            float4 va = *(const float4*)(x + (size_t)(m0 + row) * II + k0 + col);
            As[row][col] = va.x; As[row][col + 1] = va.y;
            As[row][col + 2] = va.z; As[row][col + 3] = va.w;
            float4 vb = *(const float4*)(Wx + (size_t)(n0 + row) * II + k0 + col);
            Bs[row][col] = vb.x; Bs[row][col + 1] = vb.y;
            Bs[row][col + 2] = vb.z; Bs[row][col + 3] = vb.w;
        }
        __syncthreads();
#pragma unroll
        for (int kk = 0; kk < 32; ++kk) {
            float a[4], bb[4];
#pragma unroll
            for (int u = 0; u < 4; ++u) a[u] = As[(ty << 2) + u][kk];
#pragma unroll
            for (int v = 0; v < 4; ++v) bb[v] = Bs[(tx << 2) + v][kk];
#pragma unroll
            for (int u = 0; u < 4; ++u)
#pragma unroll
                for (int v = 0; v < 4; ++v)
                    c[u][v] = fmaf(a[u], bb[v], c[u][v]);
        }
        __syncthreads();
    }
    const int n = n0 + (tx << 2);
    float4 bxv = *(const float4*)(bx + n);
    float4 bhv = *(const float4*)(bh + n);
    float4 badd = {bxv.x + bhv.x, bxv.y + bhv.y, bxv.z + bhv.z, bxv.w + bhv.w};
#pragma unroll
    for (int u = 0; u < 4; ++u) {
        int m = m0 + (ty << 2) + u;
        float4 o = {c[u][0] + badd.x, c[u][1] + badd.y,
                    c[u][2] + badd.z, c[u][3] + badd.w};
        *(float4*)(xf + (size_t)m * G4 + n) = o;
    }
}

// ---------------------------------------------------------------------------
// hebb: 4 NAMED half2 regs/thread (rows r0g+2i, r0g+2i+1; r0g = r*32+rg*8).
// ---------------------------------------------------------------------------
#define HBQ_FOREACH(X) X(0) X(1) X(2) X(3)

#define HBQ_DECL(i) h2_t hp##i = {(_Float16)0.0f, (_Float16)0.0f};
#define HBQ_OUT(i) \
    hbout[(size_t)(r0g + 2 * i) * HH + k]     = (float)hp##i.x; \
    hbout[(size_t)(r0g + 2 * i + 1) * HH + k] = (float)hp##i.y;

#define HBQ_STEP(i, au, hou, hnu) { \
    h2_t al2 = __builtin_bit_cast(h2_t, au); \
    h2_t ho2 = __builtin_bit_cast(h2_t, hou); \
    h2_t hn2 = __builtin_bit_cast(h2_t, hnu); \
    hp##i = clip2h(pkfma(mj2, ho2, hp##i)); \
    h2_t hna = hn2 * al2; \
    pp = dot2(__builtin_bit_cast(unsigned, hna), \
              __builtin_bit_cast(unsigned, hp##i), pp); }

#define HBV_STEP(i, hou) { \
    h2_t ho2 = __builtin_bit_cast(h2_t, hou); \
    hp##i = clip2h(pkfma(mj2, ho2, hp##i)); }

#define DOTW(W, HV) { \
    ac0 = dot2(W.x, HV.x, ac0); ac1 = dot2(W.y, HV.y, ac1); \
    ac2 = dot2(W.z, HV.z, ac2); ac3 = dot2(W.w, HV.w, ac3); }

#define POLL_ONE(d, s, P) \
    if (!d) { \
        u64 v = __hip_atomic_load(&P[off], __ATOMIC_RELAXED, \
                                  __HIP_MEMORY_SCOPE_AGENT); \
        if ((unsigned)(v >> 32) == tag) { \
            s = __builtin_bit_cast(float, (unsigned)v); \
            d = true; \
        } \
    }

__global__ __launch_bounds__(1024, 1) void scan_kernel(
    const float* __restrict__ xf,      // [T,B,4H], biases folded
    const uint4* __restrict__ Wd3,
    const uint4* __restrict__ alQ,
    const float* __restrict__ w_mod,
    const float* __restrict__ b_mod,
    const float* __restrict__ w_fan,
    const float* __restrict__ b_fan,
    u64* __restrict__ exData,          // [32][8][2][1024] u64 {tag|f32}
    float* __restrict__ out) {
    const int bid = blockIdx.x;
    const int r   = bid >> 5;          // role 0..7: rows r*32..r*32+31
    const int b   = bid & 31;          // batch element
    const int tid = threadIdx.x;
    const int k   = tid & (HH - 1);
    const int rg  = tid >> 8;          // 0..3
    const int r0g = r * 32 + rg * 8;   // first hebb row owned
    const int hb4 = 4 * r + rg;        // uint4 index of row r0g in hf_s

    __shared__ alignas(16) unsigned short hf_s[2][HH];
    __shared__ float fioj_s[G4];
    __shared__ float pp_s[4][HH];
    __shared__ float red_s[4];

    HBQ_FOREACH(HBQ_DECL)

    if (tid < HH) {
        hf_s[0][tid] = 0;
        hf_s[1][tid] = 0;
    }
    if (tid < 4) red_s[tid] = 0.0f;
    __syncthreads();

    const float bmod = b_mod[0];
    const float wf = w_fan[k], bf = b_fan[k], wm = w_mod[k];
    float creg = 0.0f, jreg = 0.0f, hnreg = 0.0f;

    // ---- Register-resident weights (rows r*32..+31 for column g=tid) -----
    const uint4* wb = Wd3 + ((size_t)r << 12) + (tid << 2);
    uint4 w0 = wb[0], w1 = wb[1], w2 = wb[2], w3 = wb[3];
    // ---- Register-resident alpha (4 row-pairs = 8 rows for column k) -----
    uint4 aq = alQ[(size_t)(4 * r + rg) * 256 + k];

    const float* xfp = xf + (size_t)b * G4 + tid;

    u64* myEx = exData + (size_t)((b * 8 + r) * 2) * 1024;
    const u64* pEx1 = exData + (size_t)((b * 8 + ((r + 1) & 7)) * 2) * 1024;
    const u64* pEx2 = exData + (size_t)((b * 8 + ((r + 2) & 7)) * 2) * 1024;
    const u64* pEx3 = exData + (size_t)((b * 8 + ((r + 3) & 7)) * 2) * 1024;
    const u64* pEx4 = exData + (size_t)((b * 8 + ((r + 4) & 7)) * 2) * 1024;
    const u64* pEx5 = exData + (size_t)((b * 8 + ((r + 5) & 7)) * 2) * 1024;
    const u64* pEx6 = exData + (size_t)((b * 8 + ((r + 6) & 7)) * 2) * 1024;
    const u64* pEx7 = exData + (size_t)((b * 8 + ((r + 7) & 7)) * 2) * 1024;

    for (int t = 0; t < TT; ++t) {
        const unsigned tag = (unsigned)(t + 1);
        const int off = (t & 1) * 1024 + tid;
        const uint4* hfO4 = (const uint4*)hf_s[t & 1];        // h_{t-2}
        const uint4* hfN4 = (const uint4*)hf_s[(t & 1) ^ 1];  // h_{t-1}

        float xfv = 0.0f;
        if ((tid >> 7) == r) xfv = xfp[(size_t)t * BB * G4];  // exactly-once

        // ---- Phase 1b FIRST: 1/8-K gate matvec, weights in registers ------
        float ac0 = 0.f, ac1 = 0.f, ac2 = 0.f, ac3 = 0.f;
        {
            const int hx = r << 2;
            uint4 h0 = hfN4[hx], h1 = hfN4[hx + 1];
            uint4 h2 = hfN4[hx + 2], h3 = hfN4[hx + 3];
            DOTW(w0, h0) DOTW(w1, h1) DOTW(w2, h2) DOTW(w3, h3)
        }
        float part = ((ac0 + ac1) + (ac2 + ac3)) + xfv;

        // ---- publish f/i/o quarters NOW (no plast dependence) -------------
        if (tid < 768) {
            u64 pkv = ((u64)tag << 32) |
                      (u64)__builtin_bit_cast(unsigned, part);
            __hip_atomic_store(&myEx[off], pkv, __ATOMIC_RELAXED,
                               __HIP_MEMORY_SCOPE_AGENT);
        }

        // ---- Phase 1a: eta_{t-1}; deferred hebb update + plast(t) fused ---
        float eta = tanhfast(((red_s[0] + red_s[1]) + (red_s[2] + red_s[3])) + bmod);
        float mj = fmaf(eta, wf, bf) * jreg;    // 0 at t=0
        h2_t mj2;
        mj2.x = (_Float16)mj;
        mj2.y = mj2.x;
        float pp = 0.0f;
        {
            uint4 ho = hfO4[hb4];
            uint4 hn = hfN4[hb4];
            HBQ_STEP(0, aq.x, ho.x, hn.x)
            HBQ_STEP(1, aq.y, ho.y, hn.y)
            HBQ_STEP(2, aq.z, ho.z, hn.z)
            HBQ_STEP(3, aq.w, ho.w, hn.w)
        }
        pp_s[rg][k] = pp;
        __syncthreads();                                   // B1 (pp_s ready)

        // ---- fold plast into j-quarter, publish it ------------------------
        if (tid >= 768) {
            int k2 = tid - 768;
            part += (pp_s[0][k2] + pp_s[1][k2]) + (pp_s[2][k2] + pp_s[3][k2]);
            u64 pkv = ((u64)tag << 32) |
                      (u64)__builtin_bit_cast(unsigned, part);
            __hip_atomic_store(&myEx[off], pkv, __ATOMIC_RELAXED,
                               __HIP_MEMORY_SCOPE_AGENT);
        }

        // ---- poll the 7 partner values (interleaved) ----------------------
        {
            float s1 = 0.f, s2 = 0.f, s3 = 0.f, s4 = 0.f,
                  s5 = 0.f, s6 = 0.f, s7 = 0.f;
            bool d1 = false, d2 = false, d3 = false, d4 = false,
                 d5 = false, d6 = false, d7 = false;
            do {
                POLL_ONE(d1, s1, pEx1)
                POLL_ONE(d2, s2, pEx2)
                POLL_ONE(d3, s3, pEx3)
                POLL_ONE(d4, s4, pEx4)
                POLL_ONE(d5, s5, pEx5)
                POLL_ONE(d6, s6, pEx6)
                POLL_ONE(d7, s7, pEx7)
            } while (!(d1 && d2 && d3 && d4 && d5 && d6 && d7));
            fioj_s[tid] = part + (((s1 + s2) + (s3 + s4)) + ((s5 + s6) + s7));
        }
        __syncthreads();                                   // B2 (fioj ready)

        // ---- Phase 2: cell update (redundant across roles & rg) -----------
        float fg = sigm(fioj_s[k]);
        float ig = sigm(fioj_s[HH + k]);
        float og = sigm(fioj_s[2 * HH + k]);
        float jp = fioj_s[3 * HH + k];     // plast already folded in
        jreg = tanhfast(jp);
        creg = fmaf(fg, creg, ig * jreg);
        hnreg = og * tanhfast(creg);
        if (rg == 0) {   // waves 0-3, wave-uniform
            _Float16 hh = (_Float16)hnreg;
            hf_s[t & 1][k] = __builtin_bit_cast(unsigned short, hh);
            if (r == 0) out[((size_t)t * BB + b) * HH + k] = hnreg;
            float e = creg * wm;
#pragma unroll
            for (int m = 32; m >= 1; m >>= 1) e += __shfl_xor(e, m, 64);
            if ((k & 63) == 0) red_s[k >> 6] = e;
        }
        __syncthreads();                                   // B3 (hf_s ready)
    }

    // ---- Final deferred hebb update (step 255's delta) -------------------
    {
        float eta = tanhfast(((red_s[0] + red_s[1]) + (red_s[2] + red_s[3])) + bmod);
        float mj = fmaf(eta, wf, bf) * jreg;
        h2_t mj2;
        mj2.x = (_Float16)mj;
        mj2.y = mj2.x;
        const uint4* hfO4 = (const uint4*)hf_s[0];   // h_254 (TT even)
        uint4 ho = hfO4[hb4];
        HBV_STEP(0, ho.x) HBV_STEP(1, ho.y)
        HBV_STEP(2, ho.z) HBV_STEP(3, ho.w)
    }

    const size_t HS = (size_t)TT * BB * HH;
    if (r == 0 && rg == 0) {
        out[HS + (size_t)b * HH + k]           = hnreg;  // h_255
        out[HS + BB * HH + (size_t)b * HH + k] = creg;   // c_255
    }
    float* hbout = out + HS + 2 * BB * HH + (size_t)b * HH * HH;
    HBQ_FOREACH(HBQ_OUT)
}

// ---------------------------------------------------------------------------
extern "C" void kernel_launch(void* const* d_in, const int* in_sizes, int n_in,
                              void* d_out, int out_size, void* d_ws,
                              size_t ws_size, hipStream_t stream) {
    const float* x     = (const float*)d_in[0];
    const float* Wx    = (const float*)d_in[1];
    const float* bx    = (const float*)d_in[2];
    const float* Wh    = (const float*)d_in[3];
    const float* bh    = (const float*)d_in[4];
    const float* w_mod = (const float*)d_in[5];
    const float* b_mod = (const float*)d_in[6];
    const float* w_fan = (const float*)d_in[7];
    const float* b_fan = (const float*)d_in[8];
    const float* alpha = (const float*)d_in[9];
    float* out = (float*)d_out;

    float* xf  = (float*)d_ws;                              // 32 MiB
    uint4* Wd3 = (uint4*)((char*)d_ws + 33554432);          // 512 KiB
    uint4* alQ = (uint4*)((char*)d_ws + 34078720);          // 128 KiB
    u64*   exD = (u64*)((char*)d_ws + 34209792);            // 4 MiB

    hipLaunchKernelGGL(prep_wd3, dim3(128), dim3(256), 0, stream, Wh, Wd3);
    hipLaunchKernelGGL(prep_alq, dim3(32), dim3(256), 0, stream, alpha, alQ);
    hipLaunchKernelGGL(xf_gemm, dim3(16, 128), dim3(256), 0, stream,
                       x, Wx, bx, bh, xf);
    hipLaunchKernelGGL(scan_kernel, dim3(256), dim3(1024), 0, stream,
                       xf, Wd3, alQ, w_mod, b_mod, w_fan, b_fan,
                       exD, out);
}